// Round 6
// baseline (248.246 us; speedup 1.0000x reference)
//
#include <hip/hip_runtime.h>
#include <hip/hip_bf16.h>
#include <math.h>

// qkv_attn: x[8,16384,256] fp32. kv = LN(k)^T LN(v)/HW folded into Wq (per batch).
// R6: k3 rewritten: 256-thr/32-row blocks (grid 4096, LDS 17KB -> ~7 blocks/CU),
// in-place ret into xs (rs deleted), residual x kept in bf16 regs (no epilogue
// global re-read), no weight-preload arrays (R5 showed they hurt k3).
// k1a: sqrt+div -> rsqrt (eps error 3e-5 << bf16 rounding).

#define EPSF 1e-5f

typedef __bf16 bf16x8 __attribute__((ext_vector_type(8)));
typedef __bf16 bf16x4 __attribute__((ext_vector_type(4)));
typedef float  f32x4  __attribute__((ext_vector_type(4)));

// ---------------- K0: weight prep (fp32 -> bf16, de-interleave k/v rows), zero kv accum ----
__global__ void k0_prep(const float* __restrict__ Wqkv, const float* __restrict__ Wproj,
                        __bf16* __restrict__ Wkv, __bf16* __restrict__ Wp,
                        float* __restrict__ kv) {
  int idx = blockIdx.x * 256 + threadIdx.x;   // grid 512*256 = 131072
  if (idx < 32768) kv[idx] = 0.f;             // kv accumulator [8][16][16][16]
  {
    int r = idx >> 8, c = idx & 255;
    int half = r >> 8;          // 0:k 1:v
    int rr = r & 255;
    int h = rr >> 4, d = rr & 15;
    Wkv[idx] = (__bf16)Wqkv[(h*48 + 16 + half*16 + d)*256 + c];
  }
  if (idx < 65536) Wp[idx] = (__bf16)Wproj[idx];
}

// ---------------- K1a: k,v GEMM + LN + local kv reduction ----------------
__launch_bounds__(512, 4)
__global__ void k1a(const float* __restrict__ x, const __bf16* __restrict__ Wkv,
                    const float* __restrict__ bqkv,
                    const float* __restrict__ klnw, const float* __restrict__ klnb,
                    const float* __restrict__ vlnw, const float* __restrict__ vlnb,
                    float* __restrict__ kvout) {
  __shared__ __align__(16) char smem[70656];   // xs[64][264] (33792) | tTk 8x[32][72] (36864)
  __bf16 (*xs)[264] = reinterpret_cast<__bf16(*)[264]>(smem);
  const int tid = threadIdx.x;
  const int w = tid >> 6, l = tid & 63, lr = l & 15, g = l >> 4;
  __bf16 (*tTk)[72] = reinterpret_cast<__bf16(*)[72]>(smem + 33792 + w*4608); // [c 32][r 72]
  __bf16 (*tTv)[64] = reinterpret_cast<__bf16(*)[64]>(smem + w*4096);         // [c 32][r 64] swz

  const long row0 = (long)blockIdx.x * 64;
  const int b = (int)(row0 >> 14);

  // stage x tile -> bf16 LDS
  #pragma unroll
  for (int i = 0; i < 8; ++i) {
    int idx = tid + i*512;
    int r = idx >> 6, c4 = (idx & 63) << 2;
    f32x4 v = *reinterpret_cast<const f32x4*>(x + (row0 + r)*256 + c4);
    bf16x4 pk; pk[0]=(__bf16)v[0]; pk[1]=(__bf16)v[1]; pk[2]=(__bf16)v[2]; pk[3]=(__bf16)v[3];
    *reinterpret_cast<bf16x4*>(&xs[r][c4]) = pk;
  }

  // preload ALL pass-0 (k) weight fragments: independent L2 loads in flight
  bf16x8 wk[2][8];
  #pragma unroll
  for (int cb=0;cb<2;cb++) {
    const __bf16* wp = Wkv + (size_t)(w*32 + cb*16 + lr)*256 + g*8;
    #pragma unroll
    for (int kc=0;kc<8;kc++) wk[cb][kc] = *reinterpret_cast<const bf16x8*>(wp + kc*32);
  }
  __syncthreads();

  // ---- pass 0 (k) GEMM ----
  f32x4 acc[2][4];
  for (int cb=0;cb<2;cb++) for (int rb=0;rb<4;rb++)
    for (int j=0;j<4;j++) acc[cb][rb][j]=0.f;
  #pragma unroll
  for (int kc = 0; kc < 8; ++kc) {
    const int kb = kc*32 + g*8;
    bf16x8 bf_[4];
    #pragma unroll
    for (int rb=0;rb<4;rb++)
      bf_[rb] = *reinterpret_cast<const bf16x8*>(&xs[rb*16+lr][kb]);
    #pragma unroll
    for (int cb=0;cb<2;cb++)
      #pragma unroll
      for (int rb=0;rb<4;rb++)
        acc[cb][rb] = __builtin_amdgcn_mfma_f32_16x16x32_bf16(wk[cb][kc], bf_[rb], acc[cb][rb], 0,0,0);
  }

  // preload pass-1 (v) weights while LN runs
  bf16x8 wv[2][8];
  #pragma unroll
  for (int cb=0;cb<2;cb++) {
    const __bf16* wp = Wkv + (size_t)(256 + w*32 + cb*16 + lr)*256 + g*8;
    #pragma unroll
    for (int kc=0;kc<8;kc++) wv[cb][kc] = *reinterpret_cast<const bf16x8*>(wp + kc*32);
  }

  // ---- pass 0 LN -> tTk (private, no barrier needed) ----
  #pragma unroll
  for (int cb=0;cb<2;cb++) {
    const int h = 2*w + cb;
    const f32x4 bb  = *reinterpret_cast<const f32x4*>(bqkv + h*48 + 16 + 4*g);
    const f32x4 lwv = *reinterpret_cast<const f32x4*>(klnw + h*16 + 4*g);
    const f32x4 lbv = *reinterpret_cast<const f32x4*>(klnb + h*16 + 4*g);
    #pragma unroll
    for (int rb=0;rb<4;rb++) {
      float v0 = acc[cb][rb][0] + bb[0];
      float v1 = acc[cb][rb][1] + bb[1];
      float v2 = acc[cb][rb][2] + bb[2];
      float v3 = acc[cb][rb][3] + bb[3];
      float sum = v0+v1+v2+v3;
      sum += __shfl_xor(sum, 16); sum += __shfl_xor(sum, 32);
      const float mu = sum * 0.0625f;
      const float d0=v0-mu, d1=v1-mu, d2=v2-mu, d3=v3-mu;
      float q = d0*d0 + d1*d1 + d2*d2 + d3*d3;
      q += __shfl_xor(q, 16); q += __shfl_xor(q, 32);
      const float sc = __frsqrt_rn(q * (1.f/15.f));   // 1/(std+eps) ~ rsqrt(var), eps err 3e-5
      const int rr = rb*16 + lr;
      tTk[cb*16 + 4*g+0][rr] = (__bf16)(lwv[0]*d0*sc + lbv[0]);
      tTk[cb*16 + 4*g+1][rr] = (__bf16)(lwv[1]*d1*sc + lbv[1]);
      tTk[cb*16 + 4*g+2][rr] = (__bf16)(lwv[2]*d2*sc + lbv[2]);
      tTk[cb*16 + 4*g+3][rr] = (__bf16)(lwv[3]*d3*sc + lbv[3]);
    }
  }

  // ---- pass 1 (v) GEMM ----
  for (int cb=0;cb<2;cb++) for (int rb=0;rb<4;rb++)
    for (int j=0;j<4;j++) acc[cb][rb][j]=0.f;
  #pragma unroll
  for (int kc = 0; kc < 8; ++kc) {
    const int kb = kc*32 + g*8;
    bf16x8 bf_[4];
    #pragma unroll
    for (int rb=0;rb<4;rb++)
      bf_[rb] = *reinterpret_cast<const bf16x8*>(&xs[rb*16+lr][kb]);
    #pragma unroll
    for (int cb=0;cb<2;cb++)
      #pragma unroll
      for (int rb=0;rb<4;rb++)
        acc[cb][rb] = __builtin_amdgcn_mfma_f32_16x16x32_bf16(wv[cb][kc], bf_[rb], acc[cb][rb], 0,0,0);
  }
  __syncthreads();   // ALL waves done reading xs; its space becomes tTv

  // ---- pass 1 LN -> tTv (XOR-swizzled rows) ----
  #pragma unroll
  for (int cb=0;cb<2;cb++) {
    const int h = 2*w + cb;
    const f32x4 bb  = *reinterpret_cast<const f32x4*>(bqkv + h*48 + 32 + 4*g);
    const f32x4 lwv = *reinterpret_cast<const f32x4*>(vlnw + h*16 + 4*g);
    const f32x4 lbv = *reinterpret_cast<const f32x4*>(vlnb + h*16 + 4*g);
    #pragma unroll
    for (int rb=0;rb<4;rb++) {
      float v0 = acc[cb][rb][0] + bb[0];
      float v1 = acc[cb][rb][1] + bb[1];
      float v2 = acc[cb][rb][2] + bb[2];
      float v3 = acc[cb][rb][3] + bb[3];
      float sum = v0+v1+v2+v3;
      sum += __shfl_xor(sum, 16); sum += __shfl_xor(sum, 32);
      const float mu = sum * 0.0625f;
      const float d0=v0-mu, d1=v1-mu, d2=v2-mu, d3=v3-mu;
      float q = d0*d0 + d1*d1 + d2*d2 + d3*d3;
      q += __shfl_xor(q, 16); q += __shfl_xor(q, 32);
      const float sc = __frsqrt_rn(q * (1.f/15.f));
      const int rr = rb*16 + lr;
      tTv[cb*16 + 4*g+0][rr ^ (((4*g+0)&7)<<3)] = (__bf16)(lwv[0]*d0*sc + lbv[0]);
      tTv[cb*16 + 4*g+1][rr ^ (((4*g+1)&7)<<3)] = (__bf16)(lwv[1]*d1*sc + lbv[1]);
      tTv[cb*16 + 4*g+2][rr ^ (((4*g+2)&7)<<3)] = (__bf16)(lwv[2]*d2*sc + lbv[2]);
      tTv[cb*16 + 4*g+3][rr ^ (((4*g+3)&7)<<3)] = (__bf16)(lwv[3]*d3*sc + lbv[3]);
    }
  }

  // ---- kv_h += k'^T v' (private LDS, per-wave tiles) ----
  #pragma unroll
  for (int hh=0; hh<2; ++hh) {
    f32x4 c; c[0]=0.f; c[1]=0.f; c[2]=0.f; c[3]=0.f;
    #pragma unroll
    for (int ch=0; ch<2; ++ch) {
      const int s = ch*32 + g*8;
      bf16x8 a  = *reinterpret_cast<const bf16x8*>(&tTk[hh*16 + lr][s]);
      bf16x8 bv = *reinterpret_cast<const bf16x8*>(&tTv[hh*16 + lr][s ^ ((lr&7)<<3)]);
      c = __builtin_amdgcn_mfma_f32_16x16x32_bf16(a, bv, c, 0,0,0);
    }
    float* dst = kvout + ((size_t)(b*16 + 2*w + hh) << 8);
    #pragma unroll
    for (int j=0;j<4;j++)
      atomicAdd(dst + (4*g+j)*16 + lr, c[j]);   // kv[d=4g+j][e=lr]
  }
}

// ---------------- K2: Wq_eff[b][h*16+e][c] = sum_d kv[b,h,d,e]/HW * Wq[h*48+d][c] ----------
__global__ void k2_weff(const float* __restrict__ Wqkv, const float* __restrict__ bqkv,
                        const float* __restrict__ kvin,
                        __bf16* __restrict__ Wqe, float* __restrict__ beff) {
  const int b = blockIdx.x >> 4, h = blockIdx.x & 15;
  const int c = threadIdx.x;
  __shared__ float kvs[16][16]; // [d][e]
  kvs[c >> 4][c & 15] = kvin[(b*16 + h)*256 + c] * (1.f/16384.f);
  __syncthreads();
  #pragma unroll 4
  for (int e=0;e<16;e++) {
    float acc = 0.f;
    #pragma unroll
    for (int d=0; d<16; d++)
      acc += kvs[d][e] * Wqkv[(h*48 + d)*256 + c];
    Wqe[((size_t)b*256 + h*16 + e)*256 + c] = (__bf16)acc;
  }
  if (c < 16) {
    float acc = 0.f;
    #pragma unroll
    for (int d=0; d<16; d++) acc += kvs[d][c] * bqkv[h*48 + d];
    beff[b*256 + h*16 + c] = acc;
  }
}

// ---------------- K3: fused o = x@Wq_eff^T; ret = o+beff+x (in-place); proj = ret@Wp^T;
//                  y = gelu(proj+bp) + x (residual from regs) ----------------
// 256 thr (4 waves), 32-row tile, grid 4096. Wave w owns cols w*64..w*64+63 (4 cb).
// LDS = xs only (17KB) -> ~6-7 blocks/CU; no epilogue global x re-read.
__launch_bounds__(256)
__global__ void k3_fused(const float* __restrict__ x, const __bf16* __restrict__ Wqe,
                         const float* __restrict__ beff, const __bf16* __restrict__ Wp,
                         const float* __restrict__ bproj, float* __restrict__ out) {
  __shared__ __align__(16) __bf16 xs[32][264];
  const int tid = threadIdx.x;
  const long browg = (long)blockIdx.x * 32;
  const int b = (int)(browg >> 14);
  const int w = tid>>6, l = tid&63, lr = l&15, g = l>>4;

  // stage 32x256 fp32 -> bf16 (wave w: rows w, w+4, ..., w+28, full row each)
  #pragma unroll
  for (int i = 0; i < 8; ++i) {
    int idx = tid + i*256;
    int r = idx >> 6, c4 = (idx & 63) << 2;
    f32x4 v = *reinterpret_cast<const f32x4*>(x + (browg + r)*256 + c4);
    bf16x4 pk; pk[0]=(__bf16)v[0]; pk[1]=(__bf16)v[1]; pk[2]=(__bf16)v[2]; pk[3]=(__bf16)v[3];
    *reinterpret_cast<bf16x4*>(&xs[r][c4]) = pk;
  }
  __syncthreads();

  const __bf16* Bq = Wqe + (size_t)b*65536;

  // GEMM1 (swapped): acc[cb][rb] -> col w*64+cb*16+4g+j, row rb*16+lr
  f32x4 acc[4][2];
  for (int cb=0;cb<4;cb++) for (int rb=0;rb<2;rb++)
    for (int j=0;j<4;j++) acc[cb][rb][j]=0.f;
  #pragma unroll
  for (int kc=0;kc<8;kc++) {
    const int kb = kc*32 + g*8;
    bf16x8 af[4], bf_[2];
    #pragma unroll
    for (int cb=0;cb<4;cb++)
      af[cb] = *reinterpret_cast<const bf16x8*>(Bq + (size_t)(w*64 + cb*16 + lr)*256 + kb);
    #pragma unroll
    for (int rb=0;rb<2;rb++)
      bf_[rb] = *reinterpret_cast<const bf16x8*>(&xs[rb*16+lr][kb]);
    #pragma unroll
    for (int cb=0;cb<4;cb++)
      #pragma unroll
      for (int rb=0;rb<2;rb++)
        acc[cb][rb] = __builtin_amdgcn_mfma_f32_16x16x32_bf16(af[cb], bf_[rb], acc[cb][rb], 0,0,0);
  }
  __syncthreads();   // all fragment reads of xs complete

  // ret = o + beff + x, written IN PLACE into xs; residual x stashed in regs
  bf16x4 xv[4][2];
  #pragma unroll
  for (int cb=0;cb<4;cb++) {
    const int c0 = w*64 + cb*16 + 4*g;
    const f32x4 be = *reinterpret_cast<const f32x4*>(beff + b*256 + c0);
    #pragma unroll
    for (int rb=0;rb<2;rb++) {
      const int r = rb*16 + lr;
      xv[cb][rb] = *reinterpret_cast<const bf16x4*>(&xs[r][c0]);
      bf16x4 pk;
      #pragma unroll
      for (int j=0;j<4;j++)
        pk[j] = (__bf16)(acc[cb][rb][j] + be[j] + (float)xv[cb][rb][j]);
      *reinterpret_cast<bf16x4*>(&xs[r][c0]) = pk;
    }
  }
  __syncthreads();

  // GEMM2 (swapped): proj = ret @ Wp^T
  f32x4 acc2[4][2];
  for (int cb=0;cb<4;cb++) for (int rb=0;rb<2;rb++)
    for (int j=0;j<4;j++) acc2[cb][rb][j]=0.f;
  #pragma unroll
  for (int kc=0;kc<8;kc++) {
    const int kb = kc*32 + g*8;
    bf16x8 af[4], bf_[2];
    #pragma unroll
    for (int cb=0;cb<4;cb++)
      af[cb] = *reinterpret_cast<const bf16x8*>(Wp + (size_t)(w*64 + cb*16 + lr)*256 + kb);
    #pragma unroll
    for (int rb=0;rb<2;rb++)
      bf_[rb] = *reinterpret_cast<const bf16x8*>(&xs[rb*16+lr][kb]);
    #pragma unroll
    for (int cb=0;cb<4;cb++)
      #pragma unroll
      for (int rb=0;rb<2;rb++)
        acc2[cb][rb] = __builtin_amdgcn_mfma_f32_16x16x32_bf16(af[cb], bf_[rb], acc2[cb][rb], 0,0,0);
  }

  // epilogue: y = gelu_exact(proj + bp) + x  (residual from regs, f32x4 stores)
  #pragma unroll
  for (int cb=0;cb<4;cb++) {
    const int c0 = w*64 + cb*16 + 4*g;
    const f32x4 bp4 = *reinterpret_cast<const f32x4*>(bproj + c0);
    #pragma unroll
    for (int rb=0;rb<2;rb++) {
      const long gr = browg + rb*16 + lr;
      f32x4 o;
      #pragma unroll
      for (int j=0;j<4;j++) {
        float z = acc2[cb][rb][j] + bp4[j];
        o[j] = 0.5f*z*(1.f + erff(z*0.70710678118f)) + (float)xv[cb][rb][j];
      }
      *reinterpret_cast<f32x4*>(out + gr*256 + c0) = o;
    }
  }
}

extern "C" void kernel_launch(void* const* d_in, const int* in_sizes, int n_in,
                              void* d_out, int out_size, void* d_ws, size_t ws_size,
                              hipStream_t stream) {
  const float* x    = (const float*)d_in[0];
  const float* Wqkv = (const float*)d_in[1];
  const float* bqkv = (const float*)d_in[2];
  const float* klnw = (const float*)d_in[3];
  const float* klnb = (const float*)d_in[4];
  const float* vlnw = (const float*)d_in[5];
  const float* vlnb = (const float*)d_in[6];
  const float* Wproj= (const float*)d_in[7];
  const float* bproj= (const float*)d_in[8];
  float* out = (float*)d_out;

  char* ws = (char*)d_ws;
  __bf16* Wkv = (__bf16*)(ws);                 // 512*256*2   = 262144
  __bf16* Wp  = (__bf16*)(ws + 262144);        // 256*256*2   = 131072
  float*  kv  = (float*) (ws + 393216);        // 32768*4     = 131072
  __bf16* Wqe = (__bf16*)(ws + 524288);        // 8*256*256*2 = 1048576
  float*  beff= (float*) (ws + 1572864);       // 8*256*4     = 8192

  k0_prep <<<512, 256, 0, stream>>>(Wqkv, Wproj, Wkv, Wp, kv);
  k1a     <<<2048, 512, 0, stream>>>(x, Wkv, bqkv, klnw, klnb, vlnw, vlnb, kv);
  k2_weff <<<128, 256, 0, stream>>>(Wqkv, bqkv, kv, Wqe, beff);
  k3_fused<<<4096, 256, 0, stream>>>(x, Wqe, beff, Wp, bproj, out);
}

// Round 7
// 205.312 us; speedup vs baseline: 1.2091x; 1.2091x over previous
//
#include <hip/hip_runtime.h>
#include <hip/hip_bf16.h>
#include <math.h>

// qkv_attn: x[8,16384,256] fp32. kv = LN(k)^T LN(v)/HW folded into Wq (per batch).
// R7: k3 = R4 skeleton (512thr/64rows, in-loop weight loads — best measured) +
// in-place ret into xs (LDS 34KB, was 68) + residual x stashed in bf16 regs
// (no epilogue global re-read). k1a unchanged from R6.

#define EPSF 1e-5f

typedef __bf16 bf16x8 __attribute__((ext_vector_type(8)));
typedef __bf16 bf16x4 __attribute__((ext_vector_type(4)));
typedef float  f32x4  __attribute__((ext_vector_type(4)));

// ---------------- K0: weight prep (fp32 -> bf16, de-interleave k/v rows), zero kv accum ----
__global__ void k0_prep(const float* __restrict__ Wqkv, const float* __restrict__ Wproj,
                        __bf16* __restrict__ Wkv, __bf16* __restrict__ Wp,
                        float* __restrict__ kv) {
  int idx = blockIdx.x * 256 + threadIdx.x;   // grid 512*256 = 131072
  if (idx < 32768) kv[idx] = 0.f;             // kv accumulator [8][16][16][16]
  {
    int r = idx >> 8, c = idx & 255;
    int half = r >> 8;          // 0:k 1:v
    int rr = r & 255;
    int h = rr >> 4, d = rr & 15;
    Wkv[idx] = (__bf16)Wqkv[(h*48 + 16 + half*16 + d)*256 + c];
  }
  if (idx < 65536) Wp[idx] = (__bf16)Wproj[idx];
}

// ---------------- K1a: k,v GEMM + LN + local kv reduction (unchanged from R6) ----------------
__launch_bounds__(512, 4)
__global__ void k1a(const float* __restrict__ x, const __bf16* __restrict__ Wkv,
                    const float* __restrict__ bqkv,
                    const float* __restrict__ klnw, const float* __restrict__ klnb,
                    const float* __restrict__ vlnw, const float* __restrict__ vlnb,
                    float* __restrict__ kvout) {
  __shared__ __align__(16) char smem[70656];   // xs[64][264] (33792) | tTk 8x[32][72] (36864)
  __bf16 (*xs)[264] = reinterpret_cast<__bf16(*)[264]>(smem);
  const int tid = threadIdx.x;
  const int w = tid >> 6, l = tid & 63, lr = l & 15, g = l >> 4;
  __bf16 (*tTk)[72] = reinterpret_cast<__bf16(*)[72]>(smem + 33792 + w*4608); // [c 32][r 72]
  __bf16 (*tTv)[64] = reinterpret_cast<__bf16(*)[64]>(smem + w*4096);         // [c 32][r 64] swz

  const long row0 = (long)blockIdx.x * 64;
  const int b = (int)(row0 >> 14);

  #pragma unroll
  for (int i = 0; i < 8; ++i) {
    int idx = tid + i*512;
    int r = idx >> 6, c4 = (idx & 63) << 2;
    f32x4 v = *reinterpret_cast<const f32x4*>(x + (row0 + r)*256 + c4);
    bf16x4 pk; pk[0]=(__bf16)v[0]; pk[1]=(__bf16)v[1]; pk[2]=(__bf16)v[2]; pk[3]=(__bf16)v[3];
    *reinterpret_cast<bf16x4*>(&xs[r][c4]) = pk;
  }

  bf16x8 wk[2][8];
  #pragma unroll
  for (int cb=0;cb<2;cb++) {
    const __bf16* wp = Wkv + (size_t)(w*32 + cb*16 + lr)*256 + g*8;
    #pragma unroll
    for (int kc=0;kc<8;kc++) wk[cb][kc] = *reinterpret_cast<const bf16x8*>(wp + kc*32);
  }
  __syncthreads();

  f32x4 acc[2][4];
  for (int cb=0;cb<2;cb++) for (int rb=0;rb<4;rb++)
    for (int j=0;j<4;j++) acc[cb][rb][j]=0.f;
  #pragma unroll
  for (int kc = 0; kc < 8; ++kc) {
    const int kb = kc*32 + g*8;
    bf16x8 bf_[4];
    #pragma unroll
    for (int rb=0;rb<4;rb++)
      bf_[rb] = *reinterpret_cast<const bf16x8*>(&xs[rb*16+lr][kb]);
    #pragma unroll
    for (int cb=0;cb<2;cb++)
      #pragma unroll
      for (int rb=0;rb<4;rb++)
        acc[cb][rb] = __builtin_amdgcn_mfma_f32_16x16x32_bf16(wk[cb][kc], bf_[rb], acc[cb][rb], 0,0,0);
  }

  bf16x8 wv[2][8];
  #pragma unroll
  for (int cb=0;cb<2;cb++) {
    const __bf16* wp = Wkv + (size_t)(256 + w*32 + cb*16 + lr)*256 + g*8;
    #pragma unroll
    for (int kc=0;kc<8;kc++) wv[cb][kc] = *reinterpret_cast<const bf16x8*>(wp + kc*32);
  }

  #pragma unroll
  for (int cb=0;cb<2;cb++) {
    const int h = 2*w + cb;
    const f32x4 bb  = *reinterpret_cast<const f32x4*>(bqkv + h*48 + 16 + 4*g);
    const f32x4 lwv = *reinterpret_cast<const f32x4*>(klnw + h*16 + 4*g);
    const f32x4 lbv = *reinterpret_cast<const f32x4*>(klnb + h*16 + 4*g);
    #pragma unroll
    for (int rb=0;rb<4;rb++) {
      float v0 = acc[cb][rb][0] + bb[0];
      float v1 = acc[cb][rb][1] + bb[1];
      float v2 = acc[cb][rb][2] + bb[2];
      float v3 = acc[cb][rb][3] + bb[3];
      float sum = v0+v1+v2+v3;
      sum += __shfl_xor(sum, 16); sum += __shfl_xor(sum, 32);
      const float mu = sum * 0.0625f;
      const float d0=v0-mu, d1=v1-mu, d2=v2-mu, d3=v3-mu;
      float q = d0*d0 + d1*d1 + d2*d2 + d3*d3;
      q += __shfl_xor(q, 16); q += __shfl_xor(q, 32);
      const float sc = __frsqrt_rn(q * (1.f/15.f));
      const int rr = rb*16 + lr;
      tTk[cb*16 + 4*g+0][rr] = (__bf16)(lwv[0]*d0*sc + lbv[0]);
      tTk[cb*16 + 4*g+1][rr] = (__bf16)(lwv[1]*d1*sc + lbv[1]);
      tTk[cb*16 + 4*g+2][rr] = (__bf16)(lwv[2]*d2*sc + lbv[2]);
      tTk[cb*16 + 4*g+3][rr] = (__bf16)(lwv[3]*d3*sc + lbv[3]);
    }
  }

  for (int cb=0;cb<2;cb++) for (int rb=0;rb<4;rb++)
    for (int j=0;j<4;j++) acc[cb][rb][j]=0.f;
  #pragma unroll
  for (int kc = 0; kc < 8; ++kc) {
    const int kb = kc*32 + g*8;
    bf16x8 bf_[4];
    #pragma unroll
    for (int rb=0;rb<4;rb++)
      bf_[rb] = *reinterpret_cast<const bf16x8*>(&xs[rb*16+lr][kb]);
    #pragma unroll
    for (int cb=0;cb<2;cb++)
      #pragma unroll
      for (int rb=0;rb<4;rb++)
        acc[cb][rb] = __builtin_amdgcn_mfma_f32_16x16x32_bf16(wv[cb][kc], bf_[rb], acc[cb][rb], 0,0,0);
  }
  __syncthreads();   // ALL waves done reading xs; its space becomes tTv

  #pragma unroll
  for (int cb=0;cb<2;cb++) {
    const int h = 2*w + cb;
    const f32x4 bb  = *reinterpret_cast<const f32x4*>(bqkv + h*48 + 32 + 4*g);
    const f32x4 lwv = *reinterpret_cast<const f32x4*>(vlnw + h*16 + 4*g);
    const f32x4 lbv = *reinterpret_cast<const f32x4*>(vlnb + h*16 + 4*g);
    #pragma unroll
    for (int rb=0;rb<4;rb++) {
      float v0 = acc[cb][rb][0] + bb[0];
      float v1 = acc[cb][rb][1] + bb[1];
      float v2 = acc[cb][rb][2] + bb[2];
      float v3 = acc[cb][rb][3] + bb[3];
      float sum = v0+v1+v2+v3;
      sum += __shfl_xor(sum, 16); sum += __shfl_xor(sum, 32);
      const float mu = sum * 0.0625f;
      const float d0=v0-mu, d1=v1-mu, d2=v2-mu, d3=v3-mu;
      float q = d0*d0 + d1*d1 + d2*d2 + d3*d3;
      q += __shfl_xor(q, 16); q += __shfl_xor(q, 32);
      const float sc = __frsqrt_rn(q * (1.f/15.f));
      const int rr = rb*16 + lr;
      tTv[cb*16 + 4*g+0][rr ^ (((4*g+0)&7)<<3)] = (__bf16)(lwv[0]*d0*sc + lbv[0]);
      tTv[cb*16 + 4*g+1][rr ^ (((4*g+1)&7)<<3)] = (__bf16)(lwv[1]*d1*sc + lbv[1]);
      tTv[cb*16 + 4*g+2][rr ^ (((4*g+2)&7)<<3)] = (__bf16)(lwv[2]*d2*sc + lbv[2]);
      tTv[cb*16 + 4*g+3][rr ^ (((4*g+3)&7)<<3)] = (__bf16)(lwv[3]*d3*sc + lbv[3]);
    }
  }

  #pragma unroll
  for (int hh=0; hh<2; ++hh) {
    f32x4 c; c[0]=0.f; c[1]=0.f; c[2]=0.f; c[3]=0.f;
    #pragma unroll
    for (int ch=0; ch<2; ++ch) {
      const int s = ch*32 + g*8;
      bf16x8 a  = *reinterpret_cast<const bf16x8*>(&tTk[hh*16 + lr][s]);
      bf16x8 bv = *reinterpret_cast<const bf16x8*>(&tTv[hh*16 + lr][s ^ ((lr&7)<<3)]);
      c = __builtin_amdgcn_mfma_f32_16x16x32_bf16(a, bv, c, 0,0,0);
    }
    float* dst = kvout + ((size_t)(b*16 + 2*w + hh) << 8);
    #pragma unroll
    for (int j=0;j<4;j++)
      atomicAdd(dst + (4*g+j)*16 + lr, c[j]);
  }
}

// ---------------- K2: Wq_eff[b][h*16+e][c] = sum_d kv[b,h,d,e]/HW * Wq[h*48+d][c] ----------
__global__ void k2_weff(const float* __restrict__ Wqkv, const float* __restrict__ bqkv,
                        const float* __restrict__ kvin,
                        __bf16* __restrict__ Wqe, float* __restrict__ beff) {
  const int b = blockIdx.x >> 4, h = blockIdx.x & 15;
  const int c = threadIdx.x;
  __shared__ float kvs[16][16]; // [d][e]
  kvs[c >> 4][c & 15] = kvin[(b*16 + h)*256 + c] * (1.f/16384.f);
  __syncthreads();
  #pragma unroll 4
  for (int e=0;e<16;e++) {
    float acc = 0.f;
    #pragma unroll
    for (int d=0; d<16; d++)
      acc += kvs[d][e] * Wqkv[(h*48 + d)*256 + c];
    Wqe[((size_t)b*256 + h*16 + e)*256 + c] = (__bf16)acc;
  }
  if (c < 16) {
    float acc = 0.f;
    #pragma unroll
    for (int d=0; d<16; d++) acc += kvs[d][c] * bqkv[h*48 + d];
    beff[b*256 + h*16 + c] = acc;
  }
}

// ---------------- K3: fused o = x@Wq_eff^T; ret = o+beff+x (IN PLACE in xs);
//                  proj = ret@Wp^T; y = gelu(proj+bp) + x (residual from regs) -------------
// 512 thr / 64-row tile / grid 2048 (R4 skeleton — best measured). Single xs buffer
// (33.8KB LDS). Wave w owns cols w*32..+31; per kc: 2 weight loads + 4 LDS reads + 8 MFMA.
__launch_bounds__(512, 4)
__global__ void k3_fused(const float* __restrict__ x, const __bf16* __restrict__ Wqe,
                         const float* __restrict__ beff, const __bf16* __restrict__ Wp,
                         const float* __restrict__ bproj, float* __restrict__ out) {
  __shared__ __align__(16) __bf16 xs[64][264];
  const int tid = threadIdx.x;
  const long browg = (long)blockIdx.x * 64;
  const int b = (int)(browg >> 14);
  const int w = tid>>6, l = tid&63, lr = l&15, g = l>>4;

  #pragma unroll
  for (int i = 0; i < 8; ++i) {
    int idx = tid + i*512;
    int r = idx >> 6, c4 = (idx & 63) << 2;
    f32x4 v = *reinterpret_cast<const f32x4*>(x + (browg + r)*256 + c4);
    bf16x4 pk; pk[0]=(__bf16)v[0]; pk[1]=(__bf16)v[1]; pk[2]=(__bf16)v[2]; pk[3]=(__bf16)v[3];
    *reinterpret_cast<bf16x4*>(&xs[r][c4]) = pk;
  }
  __syncthreads();

  const __bf16* Bq = Wqe + (size_t)b*65536;

  // GEMM1 (swapped): acc[cb][rb] -> col w*32+cb*16+4g+j, row rb*16+lr
  f32x4 acc[2][4];
  for (int cb=0;cb<2;cb++) for (int rb=0;rb<4;rb++)
    for (int j=0;j<4;j++) acc[cb][rb][j]=0.f;
  #pragma unroll
  for (int kc=0;kc<8;kc++) {
    const int kb = kc*32 + g*8;
    bf16x8 af[2], bf_[4];
    #pragma unroll
    for (int cb=0;cb<2;cb++)
      af[cb] = *reinterpret_cast<const bf16x8*>(Bq + (size_t)(w*32 + cb*16 + lr)*256 + kb);
    #pragma unroll
    for (int rb=0;rb<4;rb++)
      bf_[rb] = *reinterpret_cast<const bf16x8*>(&xs[rb*16+lr][kb]);
    #pragma unroll
    for (int cb=0;cb<2;cb++)
      #pragma unroll
      for (int rb=0;rb<4;rb++)
        acc[cb][rb] = __builtin_amdgcn_mfma_f32_16x16x32_bf16(af[cb], bf_[rb], acc[cb][rb], 0,0,0);
  }
  __syncthreads();   // all waves' GEMM1 reads of xs complete before overwrite

  // ret = o + beff + x, IN PLACE into xs; residual x stashed in regs
  bf16x4 xv[2][4];
  #pragma unroll
  for (int cb=0;cb<2;cb++) {
    const int c0 = w*32 + cb*16 + 4*g;
    const f32x4 be = *reinterpret_cast<const f32x4*>(beff + b*256 + c0);
    #pragma unroll
    for (int rb=0;rb<4;rb++) {
      const int r = rb*16 + lr;
      xv[cb][rb] = *reinterpret_cast<const bf16x4*>(&xs[r][c0]);
      bf16x4 pk;
      #pragma unroll
      for (int j=0;j<4;j++)
        pk[j] = (__bf16)(acc[cb][rb][j] + be[j] + (float)xv[cb][rb][j]);
      *reinterpret_cast<bf16x4*>(&xs[r][c0]) = pk;
    }
  }
  __syncthreads();

  // GEMM2 (swapped): proj = ret @ Wp^T
  f32x4 acc2[2][4];
  for (int cb=0;cb<2;cb++) for (int rb=0;rb<4;rb++)
    for (int j=0;j<4;j++) acc2[cb][rb][j]=0.f;
  #pragma unroll
  for (int kc=0;kc<8;kc++) {
    const int kb = kc*32 + g*8;
    bf16x8 af[2], bf_[4];
    #pragma unroll
    for (int cb=0;cb<2;cb++)
      af[cb] = *reinterpret_cast<const bf16x8*>(Wp + (size_t)(w*32 + cb*16 + lr)*256 + kb);
    #pragma unroll
    for (int rb=0;rb<4;rb++)
      bf_[rb] = *reinterpret_cast<const bf16x8*>(&xs[rb*16+lr][kb]);
    #pragma unroll
    for (int cb=0;cb<2;cb++)
      #pragma unroll
      for (int rb=0;rb<4;rb++)
        acc2[cb][rb] = __builtin_amdgcn_mfma_f32_16x16x32_bf16(af[cb], bf_[rb], acc2[cb][rb], 0,0,0);
  }

  // epilogue: y = gelu_exact(proj + bp) + x  (residual from regs, f32x4 stores)
  #pragma unroll
  for (int cb=0;cb<2;cb++) {
    const int c0 = w*32 + cb*16 + 4*g;
    const f32x4 bp4 = *reinterpret_cast<const f32x4*>(bproj + c0);
    #pragma unroll
    for (int rb=0;rb<4;rb++) {
      const long gr = browg + rb*16 + lr;
      f32x4 o;
      #pragma unroll
      for (int j=0;j<4;j++) {
        float z = acc2[cb][rb][j] + bp4[j];
        o[j] = 0.5f*z*(1.f + erff(z*0.70710678118f)) + (float)xv[cb][rb][j];
      }
      *reinterpret_cast<f32x4*>(out + gr*256 + c0) = o;
    }
  }
}

extern "C" void kernel_launch(void* const* d_in, const int* in_sizes, int n_in,
                              void* d_out, int out_size, void* d_ws, size_t ws_size,
                              hipStream_t stream) {
  const float* x    = (const float*)d_in[0];
  const float* Wqkv = (const float*)d_in[1];
  const float* bqkv = (const float*)d_in[2];
  const float* klnw = (const float*)d_in[3];
  const float* klnb = (const float*)d_in[4];
  const float* vlnw = (const float*)d_in[5];
  const float* vlnb = (const float*)d_in[6];
  const float* Wproj= (const float*)d_in[7];
  const float* bproj= (const float*)d_in[8];
  float* out = (float*)d_out;

  char* ws = (char*)d_ws;
  __bf16* Wkv = (__bf16*)(ws);                 // 512*256*2   = 262144
  __bf16* Wp  = (__bf16*)(ws + 262144);        // 256*256*2   = 131072
  float*  kv  = (float*) (ws + 393216);        // 32768*4     = 131072
  __bf16* Wqe = (__bf16*)(ws + 524288);        // 8*256*256*2 = 1048576
  float*  beff= (float*) (ws + 1572864);       // 8*256*4     = 8192

  k0_prep <<<512, 256, 0, stream>>>(Wqkv, Wproj, Wkv, Wp, kv);
  k1a     <<<2048, 512, 0, stream>>>(x, Wkv, bqkv, klnw, klnb, vlnw, vlnb, kv);
  k2_weff <<<128, 256, 0, stream>>>(Wqkv, bqkv, kv, Wqe, beff);
  k3_fused<<<2048, 512, 0, stream>>>(x, Wqe, beff, Wp, bproj, out);
}

// Round 8
// 193.161 us; speedup vs baseline: 1.2852x; 1.0629x over previous
//
#include <hip/hip_runtime.h>
#include <hip/hip_bf16.h>
#include <math.h>

// qkv_attn: x[8,16384,256] fp32. kv = LN(k)^T LN(v)/HW folded into Wq (per batch).
// R8: k3 = R5 structure (best measured: preloads + xs/rs 2-buffer) with epilogue fixed:
// residual read from xs LDS (x never re-read from global) and stores staged through
// LDS (rs reused as f32 buffer) for full-row 1KB coalesced writes.
// k1a unchanged (measured ~72us after R6's rsqrt).

#define EPSF 1e-5f

typedef __bf16 bf16x8 __attribute__((ext_vector_type(8)));
typedef __bf16 bf16x4 __attribute__((ext_vector_type(4)));
typedef float  f32x4  __attribute__((ext_vector_type(4)));

// ---------------- K0: weight prep (fp32 -> bf16, de-interleave k/v rows), zero kv accum ----
__global__ void k0_prep(const float* __restrict__ Wqkv, const float* __restrict__ Wproj,
                        __bf16* __restrict__ Wkv, __bf16* __restrict__ Wp,
                        float* __restrict__ kv) {
  int idx = blockIdx.x * 256 + threadIdx.x;   // grid 512*256 = 131072
  if (idx < 32768) kv[idx] = 0.f;             // kv accumulator [8][16][16][16]
  {
    int r = idx >> 8, c = idx & 255;
    int half = r >> 8;          // 0:k 1:v
    int rr = r & 255;
    int h = rr >> 4, d = rr & 15;
    Wkv[idx] = (__bf16)Wqkv[(h*48 + 16 + half*16 + d)*256 + c];
  }
  if (idx < 65536) Wp[idx] = (__bf16)Wproj[idx];
}

// ---------------- K1a: k,v GEMM + LN + local kv reduction (unchanged from R7) ----------------
__launch_bounds__(512, 4)
__global__ void k1a(const float* __restrict__ x, const __bf16* __restrict__ Wkv,
                    const float* __restrict__ bqkv,
                    const float* __restrict__ klnw, const float* __restrict__ klnb,
                    const float* __restrict__ vlnw, const float* __restrict__ vlnb,
                    float* __restrict__ kvout) {
  __shared__ __align__(16) char smem[70656];   // xs[64][264] (33792) | tTk 8x[32][72] (36864)
  __bf16 (*xs)[264] = reinterpret_cast<__bf16(*)[264]>(smem);
  const int tid = threadIdx.x;
  const int w = tid >> 6, l = tid & 63, lr = l & 15, g = l >> 4;
  __bf16 (*tTk)[72] = reinterpret_cast<__bf16(*)[72]>(smem + 33792 + w*4608); // [c 32][r 72]
  __bf16 (*tTv)[64] = reinterpret_cast<__bf16(*)[64]>(smem + w*4096);         // [c 32][r 64] swz

  const long row0 = (long)blockIdx.x * 64;
  const int b = (int)(row0 >> 14);

  #pragma unroll
  for (int i = 0; i < 8; ++i) {
    int idx = tid + i*512;
    int r = idx >> 6, c4 = (idx & 63) << 2;
    f32x4 v = *reinterpret_cast<const f32x4*>(x + (row0 + r)*256 + c4);
    bf16x4 pk; pk[0]=(__bf16)v[0]; pk[1]=(__bf16)v[1]; pk[2]=(__bf16)v[2]; pk[3]=(__bf16)v[3];
    *reinterpret_cast<bf16x4*>(&xs[r][c4]) = pk;
  }

  bf16x8 wk[2][8];
  #pragma unroll
  for (int cb=0;cb<2;cb++) {
    const __bf16* wp = Wkv + (size_t)(w*32 + cb*16 + lr)*256 + g*8;
    #pragma unroll
    for (int kc=0;kc<8;kc++) wk[cb][kc] = *reinterpret_cast<const bf16x8*>(wp + kc*32);
  }
  __syncthreads();

  f32x4 acc[2][4];
  for (int cb=0;cb<2;cb++) for (int rb=0;rb<4;rb++)
    for (int j=0;j<4;j++) acc[cb][rb][j]=0.f;
  #pragma unroll
  for (int kc = 0; kc < 8; ++kc) {
    const int kb = kc*32 + g*8;
    bf16x8 bf_[4];
    #pragma unroll
    for (int rb=0;rb<4;rb++)
      bf_[rb] = *reinterpret_cast<const bf16x8*>(&xs[rb*16+lr][kb]);
    #pragma unroll
    for (int cb=0;cb<2;cb++)
      #pragma unroll
      for (int rb=0;rb<4;rb++)
        acc[cb][rb] = __builtin_amdgcn_mfma_f32_16x16x32_bf16(wk[cb][kc], bf_[rb], acc[cb][rb], 0,0,0);
  }

  bf16x8 wv[2][8];
  #pragma unroll
  for (int cb=0;cb<2;cb++) {
    const __bf16* wp = Wkv + (size_t)(256 + w*32 + cb*16 + lr)*256 + g*8;
    #pragma unroll
    for (int kc=0;kc<8;kc++) wv[cb][kc] = *reinterpret_cast<const bf16x8*>(wp + kc*32);
  }

  #pragma unroll
  for (int cb=0;cb<2;cb++) {
    const int h = 2*w + cb;
    const f32x4 bb  = *reinterpret_cast<const f32x4*>(bqkv + h*48 + 16 + 4*g);
    const f32x4 lwv = *reinterpret_cast<const f32x4*>(klnw + h*16 + 4*g);
    const f32x4 lbv = *reinterpret_cast<const f32x4*>(klnb + h*16 + 4*g);
    #pragma unroll
    for (int rb=0;rb<4;rb++) {
      float v0 = acc[cb][rb][0] + bb[0];
      float v1 = acc[cb][rb][1] + bb[1];
      float v2 = acc[cb][rb][2] + bb[2];
      float v3 = acc[cb][rb][3] + bb[3];
      float sum = v0+v1+v2+v3;
      sum += __shfl_xor(sum, 16); sum += __shfl_xor(sum, 32);
      const float mu = sum * 0.0625f;
      const float d0=v0-mu, d1=v1-mu, d2=v2-mu, d3=v3-mu;
      float q = d0*d0 + d1*d1 + d2*d2 + d3*d3;
      q += __shfl_xor(q, 16); q += __shfl_xor(q, 32);
      const float sc = __frsqrt_rn(q * (1.f/15.f));
      const int rr = rb*16 + lr;
      tTk[cb*16 + 4*g+0][rr] = (__bf16)(lwv[0]*d0*sc + lbv[0]);
      tTk[cb*16 + 4*g+1][rr] = (__bf16)(lwv[1]*d1*sc + lbv[1]);
      tTk[cb*16 + 4*g+2][rr] = (__bf16)(lwv[2]*d2*sc + lbv[2]);
      tTk[cb*16 + 4*g+3][rr] = (__bf16)(lwv[3]*d3*sc + lbv[3]);
    }
  }

  for (int cb=0;cb<2;cb++) for (int rb=0;rb<4;rb++)
    for (int j=0;j<4;j++) acc[cb][rb][j]=0.f;
  #pragma unroll
  for (int kc = 0; kc < 8; ++kc) {
    const int kb = kc*32 + g*8;
    bf16x8 bf_[4];
    #pragma unroll
    for (int rb=0;rb<4;rb++)
      bf_[rb] = *reinterpret_cast<const bf16x8*>(&xs[rb*16+lr][kb]);
    #pragma unroll
    for (int cb=0;cb<2;cb++)
      #pragma unroll
      for (int rb=0;rb<4;rb++)
        acc[cb][rb] = __builtin_amdgcn_mfma_f32_16x16x32_bf16(wv[cb][kc], bf_[rb], acc[cb][rb], 0,0,0);
  }
  __syncthreads();   // ALL waves done reading xs; its space becomes tTv

  #pragma unroll
  for (int cb=0;cb<2;cb++) {
    const int h = 2*w + cb;
    const f32x4 bb  = *reinterpret_cast<const f32x4*>(bqkv + h*48 + 32 + 4*g);
    const f32x4 lwv = *reinterpret_cast<const f32x4*>(vlnw + h*16 + 4*g);
    const f32x4 lbv = *reinterpret_cast<const f32x4*>(vlnb + h*16 + 4*g);
    #pragma unroll
    for (int rb=0;rb<4;rb++) {
      float v0 = acc[cb][rb][0] + bb[0];
      float v1 = acc[cb][rb][1] + bb[1];
      float v2 = acc[cb][rb][2] + bb[2];
      float v3 = acc[cb][rb][3] + bb[3];
      float sum = v0+v1+v2+v3;
      sum += __shfl_xor(sum, 16); sum += __shfl_xor(sum, 32);
      const float mu = sum * 0.0625f;
      const float d0=v0-mu, d1=v1-mu, d2=v2-mu, d3=v3-mu;
      float q = d0*d0 + d1*d1 + d2*d2 + d3*d3;
      q += __shfl_xor(q, 16); q += __shfl_xor(q, 32);
      const float sc = __frsqrt_rn(q * (1.f/15.f));
      const int rr = rb*16 + lr;
      tTv[cb*16 + 4*g+0][rr ^ (((4*g+0)&7)<<3)] = (__bf16)(lwv[0]*d0*sc + lbv[0]);
      tTv[cb*16 + 4*g+1][rr ^ (((4*g+1)&7)<<3)] = (__bf16)(lwv[1]*d1*sc + lbv[1]);
      tTv[cb*16 + 4*g+2][rr ^ (((4*g+2)&7)<<3)] = (__bf16)(lwv[2]*d2*sc + lbv[2]);
      tTv[cb*16 + 4*g+3][rr ^ (((4*g+3)&7)<<3)] = (__bf16)(lwv[3]*d3*sc + lbv[3]);
    }
  }

  #pragma unroll
  for (int hh=0; hh<2; ++hh) {
    f32x4 c; c[0]=0.f; c[1]=0.f; c[2]=0.f; c[3]=0.f;
    #pragma unroll
    for (int ch=0; ch<2; ++ch) {
      const int s = ch*32 + g*8;
      bf16x8 a  = *reinterpret_cast<const bf16x8*>(&tTk[hh*16 + lr][s]);
      bf16x8 bv = *reinterpret_cast<const bf16x8*>(&tTv[hh*16 + lr][s ^ ((lr&7)<<3)]);
      c = __builtin_amdgcn_mfma_f32_16x16x32_bf16(a, bv, c, 0,0,0);
    }
    float* dst = kvout + ((size_t)(b*16 + 2*w + hh) << 8);
    #pragma unroll
    for (int j=0;j<4;j++)
      atomicAdd(dst + (4*g+j)*16 + lr, c[j]);
  }
}

// ---------------- K2: Wq_eff[b][h*16+e][c] = sum_d kv[b,h,d,e]/HW * Wq[h*48+d][c] ----------
__global__ void k2_weff(const float* __restrict__ Wqkv, const float* __restrict__ bqkv,
                        const float* __restrict__ kvin,
                        __bf16* __restrict__ Wqe, float* __restrict__ beff) {
  const int b = blockIdx.x >> 4, h = blockIdx.x & 15;
  const int c = threadIdx.x;
  __shared__ float kvs[16][16]; // [d][e]
  kvs[c >> 4][c & 15] = kvin[(b*16 + h)*256 + c] * (1.f/16384.f);
  __syncthreads();
  #pragma unroll 4
  for (int e=0;e<16;e++) {
    float acc = 0.f;
    #pragma unroll
    for (int d=0; d<16; d++)
      acc += kvs[d][e] * Wqkv[(h*48 + d)*256 + c];
    Wqe[((size_t)b*256 + h*16 + e)*256 + c] = (__bf16)acc;
  }
  if (c < 16) {
    float acc = 0.f;
    #pragma unroll
    for (int d=0; d<16; d++) acc += kvs[d][c] * bqkv[h*48 + d];
    beff[b*256 + h*16 + c] = acc;
  }
}

// ---------------- K3: fused o = x@Wq_eff^T; ret = o+beff+x -> rs; proj = ret@Wp^T;
//                  y = gelu(proj+bp) + x(xs), staged through LDS for coalesced stores -----
// R5 structure (512thr/64rows, preloads, xs+rs). Epilogue: residual from xs (no global
// re-read); rs reused as f32[32][260] staging; two 32-row passes of 1KB/row stores.
__launch_bounds__(512, 4)
__global__ void k3_fused(const float* __restrict__ x, const __bf16* __restrict__ Wqe,
                         const float* __restrict__ beff, const __bf16* __restrict__ Wp,
                         const float* __restrict__ bproj, float* __restrict__ out) {
  __shared__ __align__(16) __bf16 xs[64][264];
  __shared__ __align__(16) char rsraw[33792];
  __bf16 (*rs)[264] = reinterpret_cast<__bf16(*)[264]>(rsraw);
  float  (*fst)[260] = reinterpret_cast<float(*)[260]>(rsraw);   // 32*260*4 = 33280 <= 33792
  const int tid = threadIdx.x;
  const long browg = (long)blockIdx.x * 64;
  const int b = (int)(browg >> 14);
  const int w = tid>>6, l = tid&63, lr = l&15, g = l>>4;

  #pragma unroll
  for (int i = 0; i < 8; ++i) {
    int idx = tid + i*512;
    int r = idx >> 6, c4 = (idx & 63) << 2;
    f32x4 v = *reinterpret_cast<const f32x4*>(x + (browg + r)*256 + c4);
    bf16x4 pk; pk[0]=(__bf16)v[0]; pk[1]=(__bf16)v[1]; pk[2]=(__bf16)v[2]; pk[3]=(__bf16)v[3];
    *reinterpret_cast<bf16x4*>(&xs[r][c4]) = pk;
  }

  // preload GEMM1 weights (Wq_eff, L2-resident) during staging
  const __bf16* Bq = Wqe + (size_t)b*65536;
  bf16x8 wq[2][8];
  #pragma unroll
  for (int cb=0;cb<2;cb++) {
    const __bf16* wp = Bq + (size_t)(w*32 + cb*16 + lr)*256 + g*8;
    #pragma unroll
    for (int kc=0;kc<8;kc++) wq[cb][kc] = *reinterpret_cast<const bf16x8*>(wp + kc*32);
  }
  __syncthreads();

  f32x4 acc[2][4];
  for (int cb=0;cb<2;cb++) for (int rb=0;rb<4;rb++)
    for (int j=0;j<4;j++) acc[cb][rb][j]=0.f;
  #pragma unroll
  for (int kc=0;kc<8;kc++) {
    const int kb = kc*32 + g*8;
    bf16x8 bf_[4];
    #pragma unroll
    for (int rb=0;rb<4;rb++)
      bf_[rb] = *reinterpret_cast<const bf16x8*>(&xs[rb*16+lr][kb]);
    #pragma unroll
    for (int cb=0;cb<2;cb++)
      #pragma unroll
      for (int rb=0;rb<4;rb++)
        acc[cb][rb] = __builtin_amdgcn_mfma_f32_16x16x32_bf16(wq[cb][kc], bf_[rb], acc[cb][rb], 0,0,0);
  }

  // preload GEMM2 weights while ret-phase runs
  bf16x8 wpj[2][8];
  #pragma unroll
  for (int cb=0;cb<2;cb++) {
    const __bf16* wp = Wp + (size_t)(w*32 + cb*16 + lr)*256 + g*8;
    #pragma unroll
    for (int kc=0;kc<8;kc++) wpj[cb][kc] = *reinterpret_cast<const bf16x8*>(wp + kc*32);
  }

  // ret = o + beff + x -> rs
  #pragma unroll
  for (int cb=0;cb<2;cb++) {
    const int c0 = w*32 + cb*16 + 4*g;
    const f32x4 be = *reinterpret_cast<const f32x4*>(beff + b*256 + c0);
    #pragma unroll
    for (int rb=0;rb<4;rb++) {
      const int r = rb*16 + lr;
      bf16x4 xv = *reinterpret_cast<const bf16x4*>(&xs[r][c0]);
      bf16x4 pk;
      #pragma unroll
      for (int j=0;j<4;j++)
        pk[j] = (__bf16)(acc[cb][rb][j] + be[j] + (float)xv[j]);
      *reinterpret_cast<bf16x4*>(&rs[r][c0]) = pk;
    }
  }
  __syncthreads();

  f32x4 acc2[2][4];
  for (int cb=0;cb<2;cb++) for (int rb=0;rb<4;rb++)
    for (int j=0;j<4;j++) acc2[cb][rb][j]=0.f;
  #pragma unroll
  for (int kc=0;kc<8;kc++) {
    const int kb = kc*32 + g*8;
    bf16x8 bf_[4];
    #pragma unroll
    for (int rb=0;rb<4;rb++)
      bf_[rb] = *reinterpret_cast<const bf16x8*>(&rs[rb*16+lr][kb]);
    #pragma unroll
    for (int cb=0;cb<2;cb++)
      #pragma unroll
      for (int rb=0;rb<4;rb++)
        acc2[cb][rb] = __builtin_amdgcn_mfma_f32_16x16x32_bf16(wpj[cb][kc], bf_[rb], acc2[cb][rb], 0,0,0);
  }
  __syncthreads();   // all GEMM2 reads of rs done; rs region becomes fst

  // epilogue in two 32-row passes: gelu+residual -> fst (LDS), then 1KB/row coalesced stores
  #pragma unroll
  for (int half=0; half<2; ++half) {
    #pragma unroll
    for (int cb=0;cb<2;cb++) {
      const int c0 = w*32 + cb*16 + 4*g;
      const f32x4 bp4 = *reinterpret_cast<const f32x4*>(bproj + c0);
      #pragma unroll
      for (int rbh=0;rbh<2;rbh++) {
        const int rb = half*2 + rbh;
        const int r = rb*16 + lr;
        bf16x4 xv = *reinterpret_cast<const bf16x4*>(&xs[r][c0]);
        f32x4 o;
        #pragma unroll
        for (int j=0;j<4;j++) {
          float z = acc2[cb][rb][j] + bp4[j];
          o[j] = 0.5f*z*(1.f + erff(z*0.70710678118f)) + (float)xv[j];
        }
        *reinterpret_cast<f32x4*>(&fst[r - half*32][c0]) = o;
      }
    }
    __syncthreads();
    #pragma unroll
    for (int i=0;i<4;i++) {
      int idx = tid + i*512;               // 2048 chunks = 32 rows * 64
      int r32 = idx >> 6, c4 = (idx & 63) << 2;
      f32x4 v = *reinterpret_cast<const f32x4*>(&fst[r32][c4]);
      *reinterpret_cast<f32x4*>(out + (browg + half*32 + r32)*256 + c4) = v;
    }
    if (half == 0) __syncthreads();        // fst reads done before pass-1 overwrites
  }
}

extern "C" void kernel_launch(void* const* d_in, const int* in_sizes, int n_in,
                              void* d_out, int out_size, void* d_ws, size_t ws_size,
                              hipStream_t stream) {
  const float* x    = (const float*)d_in[0];
  const float* Wqkv = (const float*)d_in[1];
  const float* bqkv = (const float*)d_in[2];
  const float* klnw = (const float*)d_in[3];
  const float* klnb = (const float*)d_in[4];
  const float* vlnw = (const float*)d_in[5];
  const float* vlnb = (const float*)d_in[6];
  const float* Wproj= (const float*)d_in[7];
  const float* bproj= (const float*)d_in[8];
  float* out = (float*)d_out;

  char* ws = (char*)d_ws;
  __bf16* Wkv = (__bf16*)(ws);                 // 512*256*2   = 262144
  __bf16* Wp  = (__bf16*)(ws + 262144);        // 256*256*2   = 131072
  float*  kv  = (float*) (ws + 393216);        // 32768*4     = 131072
  __bf16* Wqe = (__bf16*)(ws + 524288);        // 8*256*256*2 = 1048576
  float*  beff= (float*) (ws + 1572864);       // 8*256*4     = 8192

  k0_prep <<<512, 256, 0, stream>>>(Wqkv, Wproj, Wkv, Wp, kv);
  k1a     <<<2048, 512, 0, stream>>>(x, Wkv, bqkv, klnw, klnb, vlnw, vlnb, kv);
  k2_weff <<<128, 256, 0, stream>>>(Wqkv, bqkv, kv, Wqe, beff);
  k3_fused<<<2048, 512, 0, stream>>>(x, Wqe, beff, Wp, bproj, out);
}